// Round 13
// baseline (62.977 us; speedup 1.0000x reference)
//
#include <hip/hip_runtime.h>
#include <float.h>

#define BB 8
#define TT 20
#define NN 512
#define DD 64
#define BT (BB*TT)

typedef __bf16 bf16x8 __attribute__((ext_vector_type(8)));
typedef __bf16 bf16x4 __attribute__((ext_vector_type(4)));
typedef float f32x4 __attribute__((ext_vector_type(4)));

// ---------- K1: transpose->ht + bf16 copy->hb16 + partial mean + colinfo(f2) + compaction ----------
__global__ __launch_bounds__(256) void kpre(const float* __restrict__ h,
                                            const float* __restrict__ vel,
                                            const int* __restrict__ mask,
                                            __bf16* __restrict__ ht,
                                            __bf16* __restrict__ hb16,
                                            float* __restrict__ hpart,
                                            int* __restrict__ cpart,
                                            float2* __restrict__ colinfo,
                                            int* __restrict__ rows) {
    int bx = blockIdx.x;
    int bt = bx >> 3, slice = bx & 7;
    int n0 = slice * 64;
    int tid = threadIdx.x;
    const float* hp = h + ((size_t)bt * NN + n0) * DD;
    const int* mp = mask + (size_t)bt * NN + n0;
    short* htp = (short*)(ht + (size_t)bt * DD * NN) + n0;

    __shared__ __bf16 t[64][72];
    __shared__ float sred[16][64];

    int d4 = (tid & 15) << 2;
    int nl0 = tid >> 4;
    float s0 = 0.f, s1 = 0.f, s2 = 0.f, s3 = 0.f;
#pragma unroll
    for (int it = 0; it < 4; ++it) {
        int nl = it * 16 + nl0;
        float4 v = *(const float4*)(hp + (size_t)nl * DD + d4);
        if (mp[nl]) { s0 += v.x; s1 += v.y; s2 += v.z; s3 += v.w; }
        __bf16 b0 = (__bf16)v.x, b1 = (__bf16)v.y, b2 = (__bf16)v.z, b3 = (__bf16)v.w;
        t[d4 + 0][nl] = b0;
        t[d4 + 1][nl] = b1;
        t[d4 + 2][nl] = b2;
        t[d4 + 3][nl] = b3;
        bf16x4 pv = {b0, b1, b2, b3};
        *(bf16x4*)(hb16 + ((size_t)bt * NN + n0 + nl) * DD + d4) = pv;
    }
    int g = tid >> 4;
    sred[g][d4 + 0] = s0; sred[g][d4 + 1] = s1;
    sred[g][d4 + 2] = s2; sred[g][d4 + 3] = s3;
    __syncthreads();
    // ht store: 512 x 16B chunks (64 d-rows x 8 chunks), 2 iters of 256 thr
#pragma unroll
    for (int it = 0; it < 2; ++it) {
        int chunk = it * 256 + tid;
        int d = chunk >> 3, s = chunk & 7;
        *(uint4*)(htp + (size_t)d * NN + 8 * s) = *(const uint4*)(&t[d][8 * s]);
    }
    if (tid < 64) {
        float tot = 0.f;
#pragma unroll
        for (int k = 0; k < 16; ++k) tot += sred[k][tid];
        hpart[(size_t)bx * DD + tid] = tot;
    }
    if (tid < 64) {                       // wave 0: colinfo + per-slice compaction
        int j = n0 + tid;
        float2 v = ((const float2*)vel)[(size_t)bt * NN + j];
        int m = mp[tid];
        float2 cw;
        cw.x = m ? v.x : 1e18f;
        cw.y = m ? v.y : 1e18f;           // masked -> logit ~ -2e36 -> exp = 0
        colinfo[(size_t)bt * NN + j] = cw;
        unsigned long long bal = __ballot(m != 0);
        int pos = __popcll(bal & ((1ull << tid) - 1ull));
        if (tid == 0) cpart[bx] = __popcll(bal);
        if (m) rows[(size_t)bt * NN + n0 + pos] = j;
    }
}

// ---------- K2: inline beta + temporal pass, reading bf16 h copy ----------
__global__ __launch_bounds__(256) void ktempbeta(const __bf16* __restrict__ hb16,
                                                 const int* __restrict__ mask,
                                                 const float* __restrict__ hpart,
                                                 const int* __restrict__ cpart,
                                                 float* __restrict__ out) {
    int b = blockIdx.x >> 5;
    int q4 = (blockIdx.x & 31) * 256 + threadIdx.x;  // 0..8191 bf16x4 groups
    int n = q4 >> 4;
    int tid = threadIdx.x;
    __shared__ float hm[TT][DD];
    __shared__ float mbuf[TT][TT];
    __shared__ float cf[TT][TT];
    __shared__ float invc[TT];
    if (tid < TT) {
        int c = 0;
#pragma unroll
        for (int k = 0; k < 8; ++k) c += cpart[(b * TT + tid) * 8 + k];
        invc[tid] = 1.f / fmaxf((float)c, 1.f);
    }
    __syncthreads();
    for (int idx = tid; idx < TT * DD; idx += 256) {
        int t = idx >> 6, d = idx & 63;
        const float* pp = hpart + ((size_t)(b * TT + t) * 8) * DD + d;
        float s = 0.f;
#pragma unroll
        for (int k = 0; k < 8; ++k) s += pp[k * DD];
        hm[t][d] = s * invc[t];
    }
    __syncthreads();
    for (int p = tid; p < TT * TT; p += 256) {
        int t = p / TT, u = p % TT;
        float s = 0.f;
        for (int d = 0; d < DD; ++d) s += hm[t][d] * hm[u][d];
        mbuf[t][u] = s;
    }
    __syncthreads();
    if (tid < TT) {
        float mx = -FLT_MAX;
        for (int u = 0; u < TT; ++u) mx = fmaxf(mx, mbuf[tid][u]);
        float e[TT]; float sum = 0.f;
        for (int u = 0; u < TT; ++u) { e[u] = __expf(mbuf[tid][u] - mx); sum += e[u]; }
        float inv = 1.f / sum;
        for (int u = 0; u < TT; ++u)
            cf[tid][u] = e[u] * inv + (tid == u ? 1.f : 0.f);
    }
    __syncthreads();
    const bf16x4* hp = (const bf16x4*)hb16 + (size_t)b * TT * 8192;
    float4* op = (float4*)out + (size_t)b * TT * 8192;
    const int* mp = mask + (size_t)b * TT * NN;
    float4 hv[TT];
#pragma unroll
    for (int u = 0; u < TT; ++u) {
        bf16x4 x = hp[(size_t)u * 8192 + q4];
        hv[u].x = (float)x[0]; hv[u].y = (float)x[1];
        hv[u].z = (float)x[2]; hv[u].w = (float)x[3];
    }
    float4 z = {0.f, 0.f, 0.f, 0.f};
#pragma unroll
    for (int t = 0; t < TT; ++t) {
        float4 a = z;
#pragma unroll
        for (int u = 0; u < TT; ++u) {
            float c = cf[t][u];
            a.x += c * hv[u].x; a.y += c * hv[u].y;
            a.z += c * hv[u].z; a.w += c * hv[u].w;
        }
        int m = mp[(size_t)t * NN + n];
        op[(size_t)t * 8192 + q4] = m ? a : z;
    }
}

// ---------- K3: spatial attention, MFMA, quarter-j LDS staging -> 6 blocks/CU ----------
__global__ __launch_bounds__(256, 6) void kspatial(const float* __restrict__ adj,
                                                   const float* __restrict__ vel,
                                                   const int* __restrict__ cpart,
                                                   const int* __restrict__ rows,
                                                   const float2* __restrict__ colinfo,
                                                   const __bf16* __restrict__ ht,
                                                   float* __restrict__ out) {
    int bx = blockIdx.x;
    int x = bx & 7;
    int m8 = bx >> 3;                  // 0..159
    int bt = x * 20 + (m8 >> 3);
    int i0 = (m8 & 7) * 64;

    const int* cp = cpart + bt * 8;
    int cs[8];
#pragma unroll
    for (int s = 0; s < 8; ++s) cs[s] = cp[s];
    int n_act = 0;
#pragma unroll
    for (int s = 0; s < 8; ++s) n_act += cs[s];
    if (i0 >= n_act) return;

    int tid = threadIdx.x;
    int w = tid >> 6, lane = tid & 63;  // w = row-group 0..3
    int arow = lane & 15;               // A row / C col index
    int kg = lane >> 4;                 // k-group 0..3

    __shared__ __bf16 hs[64][136];      // quarter-tile: 64 d x 128 j (+8 pad) = 17.4KB
    __shared__ float2 vc[NN];           // 4KB velocity columns

    vc[tid] = colinfo[(size_t)bt * NN + tid];
    vc[256 + tid] = colinfo[(size_t)bt * NN + 256 + tid];

    int slot = i0 + w * 16 + arow;
    int slotc = slot < n_act ? slot : n_act - 1;
    int row = 0, base = 0;
#pragma unroll
    for (int s = 0; s < 8; ++s) {
        if (slotc >= base && slotc < base + cs[s])
            row = rows[(size_t)bt * NN + s * 64 + (slotc - base)];
        base += cs[s];
    }
    float2 rv = ((const float2*)vel)[(size_t)bt * NN + row];
    float vx2 = 2.f * rv.x, vy2 = 2.f * rv.y;

    const float* arowp = adj + ((size_t)bt * NN + row) * NN;
    const ushort* htb = (const ushort*)(ht + (size_t)bt * DD * NN);

    f32x4 zero = {0.f, 0.f, 0.f, 0.f};
    f32x4 acc[4];
#pragma unroll
    for (int nt = 0; nt < 4; ++nt) acc[nt] = zero;
    float lsum = 0.f;

#pragma unroll
    for (int quar = 0; quar < 4; ++quar) {
        __syncthreads();                 // hs safe to overwrite; covers vc on first pass
        const ushort* src = htb + quar * 128;
#pragma unroll
        for (int it = 0; it < 4; ++it) {
            int chunk = it * 256 + tid;  // 0..1023 16B-chunks
            int r = chunk >> 4;          // d-row (16 chunks/row)
            int cc = chunk & 15;
            *(uint4*)(&hs[r][cc * 8]) = *(const uint4*)(src + (size_t)r * NN + cc * 8);
        }
        __syncthreads();

        const float* ap = arowp + quar * 128;
        const float2* vcp = &vc[quar * 128];
        f32x4 c01 = *(const f32x4*)(ap + kg * 8);
        f32x4 c23 = *(const f32x4*)(ap + kg * 8 + 4);
#pragma unroll
        for (int c = 0; c < 4; ++c) {
            f32x4 n01, n23;
            if (c < 3) {
                n01 = *(const f32x4*)(ap + kg * 8 + (c + 1) * 32);
                n23 = *(const f32x4*)(ap + kg * 8 + (c + 1) * 32 + 4);
            }
            int jb = kg * 8 + c * 32;
            float p[8];
#pragma unroll
            for (int e = 0; e < 8; ++e) {
                float av = (e < 4) ? c01[e] : c23[e - 4];
                float2 cc2 = vcp[jb + e];
                float l = av + cc2.x * (vx2 - cc2.x) + cc2.y * (vy2 - cc2.y);
                p[e] = __expf(l);
            }
            lsum += ((p[0] + p[1]) + (p[2] + p[3])) + ((p[4] + p[5]) + (p[6] + p[7]));
            bf16x8 af;
#pragma unroll
            for (int e = 0; e < 8; ++e) af[e] = (__bf16)p[e];
#pragma unroll
            for (int nt = 0; nt < 4; ++nt) {
                bf16x8 bf = *(const bf16x8*)(&hs[nt * 16 + arow][jb]);
                acc[nt] = __builtin_amdgcn_mfma_f32_16x16x32_bf16(af, bf, acc[nt], 0, 0, 0);
            }
            c01 = n01; c23 = n23;
        }
    }

    lsum += __shfl_xor(lsum, 16, 64);
    lsum += __shfl_xor(lsum, 32, 64);
    float inv = 1.0f / fmaxf(lsum, 1e-8f);

    float* op = out + (size_t)bt * NN * DD;
#pragma unroll
    for (int q = 0; q < 4; ++q) {
        int cr = kg * 4 + q;
        int s2 = i0 + w * 16 + cr;
        int r2 = __shfl(row, cr, 64);
        float iv = __shfl(inv, cr, 64);
        if (s2 < n_act) {
#pragma unroll
            for (int nt = 0; nt < 4; ++nt) {
                size_t o = (size_t)r2 * DD + nt * 16 + arow;
                op[o] = op[o] + acc[nt][q] * iv;
            }
        }
    }
}

extern "C" void kernel_launch(void* const* d_in, const int* in_sizes, int n_in,
                              void* d_out, int out_size, void* d_ws, size_t ws_size,
                              hipStream_t stream) {
    const float* h   = (const float*)d_in[0];
    const float* vel = (const float*)d_in[1];
    const float* adj = (const float*)d_in[2];
    const int* mask  = (const int*)d_in[3];
    float* out = (float*)d_out;

    char* ws = (char*)d_ws;
    __bf16* ht      = (__bf16*)ws;                       ws += (size_t)BT * DD * NN * 2;
    __bf16* hb16    = (__bf16*)ws;                       ws += (size_t)BT * NN * DD * 2;
    float2* colinfo = (float2*)ws;                       ws += (size_t)BT * NN * 8;
    float* hpart    = (float*)ws;                        ws += (size_t)BT * 8 * DD * 4;
    int* cpart      = (int*)ws;                          ws += (size_t)BT * 8 * 4;
    int* rows       = (int*)ws;

    kpre<<<BT * 8, 256, 0, stream>>>(h, vel, mask, ht, hb16, hpart, cpart, colinfo, rows);
    ktempbeta<<<BB * 32, 256, 0, stream>>>(hb16, mask, hpart, cpart, out);
    kspatial<<<BT * 8, 256, 0, stream>>>(adj, vel, cpart, rows, colinfo, ht, out);
}

// Round 14
// 54.454 us; speedup vs baseline: 1.1565x; 1.1565x over previous
//
#include <hip/hip_runtime.h>
#include <float.h>

#define BB 8
#define TT 20
#define NN 512
#define DD 64
#define BT (BB*TT)

typedef __bf16 bf16x8 __attribute__((ext_vector_type(8)));
typedef __bf16 bf16x4 __attribute__((ext_vector_type(4)));
typedef float f32x4 __attribute__((ext_vector_type(4)));

// ---------- K1: transpose->ht + bf16 copy->hb16 + partial mean + colinfo(f2) + compaction ----------
__global__ __launch_bounds__(256) void kpre(const float* __restrict__ h,
                                            const float* __restrict__ vel,
                                            const int* __restrict__ mask,
                                            __bf16* __restrict__ ht,
                                            __bf16* __restrict__ hb16,
                                            float* __restrict__ hpart,
                                            int* __restrict__ cpart,
                                            float2* __restrict__ colinfo,
                                            int* __restrict__ rows) {
    int bx = blockIdx.x;
    int bt = bx >> 3, slice = bx & 7;
    int n0 = slice * 64;
    int tid = threadIdx.x;
    const float* hp = h + ((size_t)bt * NN + n0) * DD;
    const int* mp = mask + (size_t)bt * NN + n0;
    short* htp = (short*)(ht + (size_t)bt * DD * NN) + n0;

    __shared__ __bf16 t[64][72];
    __shared__ float sred[16][64];

    int d4 = (tid & 15) << 2;
    int nl0 = tid >> 4;
    float s0 = 0.f, s1 = 0.f, s2 = 0.f, s3 = 0.f;
#pragma unroll
    for (int it = 0; it < 4; ++it) {
        int nl = it * 16 + nl0;
        float4 v = *(const float4*)(hp + (size_t)nl * DD + d4);
        if (mp[nl]) { s0 += v.x; s1 += v.y; s2 += v.z; s3 += v.w; }
        __bf16 b0 = (__bf16)v.x, b1 = (__bf16)v.y, b2 = (__bf16)v.z, b3 = (__bf16)v.w;
        t[d4 + 0][nl] = b0;
        t[d4 + 1][nl] = b1;
        t[d4 + 2][nl] = b2;
        t[d4 + 3][nl] = b3;
        bf16x4 pv = {b0, b1, b2, b3};
        *(bf16x4*)(hb16 + ((size_t)bt * NN + n0 + nl) * DD + d4) = pv;
    }
    int g = tid >> 4;
    sred[g][d4 + 0] = s0; sred[g][d4 + 1] = s1;
    sred[g][d4 + 2] = s2; sred[g][d4 + 3] = s3;
    __syncthreads();
    // ht store: 512 x 16B chunks (64 d-rows x 8 chunks)
#pragma unroll
    for (int it = 0; it < 2; ++it) {
        int chunk = it * 256 + tid;
        int d = chunk >> 3, s = chunk & 7;
        *(uint4*)(htp + (size_t)d * NN + 8 * s) = *(const uint4*)(&t[d][8 * s]);
    }
    if (tid < 64) {
        float tot = 0.f;
#pragma unroll
        for (int k = 0; k < 16; ++k) tot += sred[k][tid];
        hpart[(size_t)bx * DD + tid] = tot;
    }
    if (tid < 64) {                       // wave 0: colinfo + per-slice compaction
        int j = n0 + tid;
        float2 v = ((const float2*)vel)[(size_t)bt * NN + j];
        int m = mp[tid];
        float2 cw;
        cw.x = m ? v.x : 1e18f;
        cw.y = m ? v.y : 1e18f;           // masked -> logit ~ -2e36 -> exp = 0
        colinfo[(size_t)bt * NN + j] = cw;
        unsigned long long bal = __ballot(m != 0);
        int pos = __popcll(bal & ((1ull << tid) - 1ull));
        if (tid == 0) cpart[bx] = __popcll(bal);
        if (m) rows[(size_t)bt * NN + n0 + pos] = j;
    }
}

// ---------- K2: inline beta + temporal pass; bf16x2 grain, 2 waves/SIMD ----------
__global__ __launch_bounds__(256) void ktempbeta(const __bf16* __restrict__ hb16,
                                                 const int* __restrict__ mask,
                                                 const float* __restrict__ hpart,
                                                 const int* __restrict__ cpart,
                                                 float* __restrict__ out) {
    int b = blockIdx.x >> 6;
    int q2 = (blockIdx.x & 63) * 256 + threadIdx.x;  // 0..16383 bf16x2 groups
    int n = q2 >> 5;
    int tid = threadIdx.x;
    __shared__ float hm[TT][DD];
    __shared__ float mbuf[TT][TT];
    __shared__ float cf[TT][TT];
    __shared__ float invc[TT];
    if (tid < TT) {
        int c = 0;
#pragma unroll
        for (int k = 0; k < 8; ++k) c += cpart[(b * TT + tid) * 8 + k];
        invc[tid] = 1.f / fmaxf((float)c, 1.f);
    }
    __syncthreads();
    for (int idx = tid; idx < TT * DD; idx += 256) {
        int t = idx >> 6, d = idx & 63;
        const float* pp = hpart + ((size_t)(b * TT + t) * 8) * DD + d;
        float s = 0.f;
#pragma unroll
        for (int k = 0; k < 8; ++k) s += pp[k * DD];
        hm[t][d] = s * invc[t];
    }
    __syncthreads();
    for (int p = tid; p < TT * TT; p += 256) {
        int t = p / TT, u = p % TT;
        float s = 0.f;
        for (int d = 0; d < DD; ++d) s += hm[t][d] * hm[u][d];
        mbuf[t][u] = s;
    }
    __syncthreads();
    if (tid < TT) {
        float mx = -FLT_MAX;
        for (int u = 0; u < TT; ++u) mx = fmaxf(mx, mbuf[tid][u]);
        float e[TT]; float sum = 0.f;
        for (int u = 0; u < TT; ++u) { e[u] = __expf(mbuf[tid][u] - mx); sum += e[u]; }
        float inv = 1.f / sum;
        for (int u = 0; u < TT; ++u)
            cf[tid][u] = e[u] * inv + (tid == u ? 1.f : 0.f);
    }
    __syncthreads();
    const unsigned int* hp = (const unsigned int*)hb16 + (size_t)b * TT * 16384;
    float2* op = (float2*)out + (size_t)b * TT * 16384;
    const int* mp = mask + (size_t)b * TT * NN;
    float2 hv[TT];
#pragma unroll
    for (int u = 0; u < TT; ++u) {
        unsigned int x = hp[(size_t)u * 16384 + q2];
        hv[u].x = __uint_as_float(x << 16);
        hv[u].y = __uint_as_float(x & 0xffff0000u);
    }
    float2 z = {0.f, 0.f};
#pragma unroll
    for (int t = 0; t < TT; ++t) {
        float2 a = z;
#pragma unroll
        for (int u = 0; u < TT; ++u) {
            float c = cf[t][u];
            a.x += c * hv[u].x; a.y += c * hv[u].y;
        }
        int m = mp[(size_t)t * NN + n];
        op[(size_t)t * 16384 + q2] = m ? a : z;
    }
}

// ---------- K3: spatial attention, MFMA, half-j LDS staging, 4 blocks/CU (R12 config) ----------
__global__ __launch_bounds__(256, 4) void kspatial(const float* __restrict__ adj,
                                                   const float* __restrict__ vel,
                                                   const int* __restrict__ cpart,
                                                   const int* __restrict__ rows,
                                                   const float2* __restrict__ colinfo,
                                                   const __bf16* __restrict__ ht,
                                                   float* __restrict__ out) {
    int bx = blockIdx.x;
    int x = bx & 7;
    int m8 = bx >> 3;                  // 0..159
    int bt = x * 20 + (m8 >> 3);
    int i0 = (m8 & 7) * 64;

    const int* cp = cpart + bt * 8;
    int cs[8];
#pragma unroll
    for (int s = 0; s < 8; ++s) cs[s] = cp[s];
    int n_act = 0;
#pragma unroll
    for (int s = 0; s < 8; ++s) n_act += cs[s];
    if (i0 >= n_act) return;

    int tid = threadIdx.x;
    int w = tid >> 6, lane = tid & 63;  // w = row-group 0..3
    int arow = lane & 15;               // A row / C col index
    int kg = lane >> 4;                 // k-group 0..3

    __shared__ __bf16 hs[64][264];      // half-tile: 64 d x 256 j (+8 pad)
    __shared__ float2 vc[NN];           // 4KB velocity columns

    vc[tid] = colinfo[(size_t)bt * NN + tid];
    vc[256 + tid] = colinfo[(size_t)bt * NN + 256 + tid];

    int slot = i0 + w * 16 + arow;
    int slotc = slot < n_act ? slot : n_act - 1;
    int row = 0, base = 0;
#pragma unroll
    for (int s = 0; s < 8; ++s) {
        if (slotc >= base && slotc < base + cs[s])
            row = rows[(size_t)bt * NN + s * 64 + (slotc - base)];
        base += cs[s];
    }
    float2 rv = ((const float2*)vel)[(size_t)bt * NN + row];
    float vx2 = 2.f * rv.x, vy2 = 2.f * rv.y;

    const float* arowp = adj + ((size_t)bt * NN + row) * NN;
    const ushort* htb = (const ushort*)(ht + (size_t)bt * DD * NN);

    f32x4 zero = {0.f, 0.f, 0.f, 0.f};
    f32x4 acc[4];
#pragma unroll
    for (int nt = 0; nt < 4; ++nt) acc[nt] = zero;
    float lsum = 0.f;

#pragma unroll
    for (int half = 0; half < 2; ++half) {
        __syncthreads();                 // hs safe to overwrite; also covers vc on half 0
        const ushort* src = htb + half * 256;
#pragma unroll
        for (int it = 0; it < 8; ++it) {
            int chunk = it * 256 + tid;  // 0..2047 16B-chunks
            int r = chunk >> 5;          // d-row (32 chunks/row)
            int cc = chunk & 31;
            *(uint4*)(&hs[r][cc * 8]) = *(const uint4*)(src + (size_t)r * NN + cc * 8);
        }
        __syncthreads();

        const float* ap = arowp + half * 256;
        const float2* vcp = &vc[half * 256];
        f32x4 c01 = *(const f32x4*)(ap + kg * 8);
        f32x4 c23 = *(const f32x4*)(ap + kg * 8 + 4);
#pragma unroll
        for (int c = 0; c < 8; ++c) {
            f32x4 n01, n23;
            if (c < 7) {
                n01 = *(const f32x4*)(ap + kg * 8 + (c + 1) * 32);
                n23 = *(const f32x4*)(ap + kg * 8 + (c + 1) * 32 + 4);
            }
            int jb = kg * 8 + c * 32;
            float p[8];
#pragma unroll
            for (int e = 0; e < 8; ++e) {
                float av = (e < 4) ? c01[e] : c23[e - 4];
                float2 cc2 = vcp[jb + e];
                float l = av + cc2.x * (vx2 - cc2.x) + cc2.y * (vy2 - cc2.y);
                p[e] = __expf(l);
            }
            lsum += ((p[0] + p[1]) + (p[2] + p[3])) + ((p[4] + p[5]) + (p[6] + p[7]));
            bf16x8 af;
#pragma unroll
            for (int e = 0; e < 8; ++e) af[e] = (__bf16)p[e];
#pragma unroll
            for (int nt = 0; nt < 4; ++nt) {
                bf16x8 bf = *(const bf16x8*)(&hs[nt * 16 + arow][jb]);
                acc[nt] = __builtin_amdgcn_mfma_f32_16x16x32_bf16(af, bf, acc[nt], 0, 0, 0);
            }
            c01 = n01; c23 = n23;
        }
    }

    lsum += __shfl_xor(lsum, 16, 64);
    lsum += __shfl_xor(lsum, 32, 64);
    float inv = 1.0f / fmaxf(lsum, 1e-8f);

    float* op = out + (size_t)bt * NN * DD;
#pragma unroll
    for (int q = 0; q < 4; ++q) {
        int cr = kg * 4 + q;
        int s2 = i0 + w * 16 + cr;
        int r2 = __shfl(row, cr, 64);
        float iv = __shfl(inv, cr, 64);
        if (s2 < n_act) {
#pragma unroll
            for (int nt = 0; nt < 4; ++nt) {
                size_t o = (size_t)r2 * DD + nt * 16 + arow;
                op[o] = op[o] + acc[nt][q] * iv;
            }
        }
    }
}

extern "C" void kernel_launch(void* const* d_in, const int* in_sizes, int n_in,
                              void* d_out, int out_size, void* d_ws, size_t ws_size,
                              hipStream_t stream) {
    const float* h   = (const float*)d_in[0];
    const float* vel = (const float*)d_in[1];
    const float* adj = (const float*)d_in[2];
    const int* mask  = (const int*)d_in[3];
    float* out = (float*)d_out;

    char* ws = (char*)d_ws;
    __bf16* ht      = (__bf16*)ws;                       ws += (size_t)BT * DD * NN * 2;
    __bf16* hb16    = (__bf16*)ws;                       ws += (size_t)BT * NN * DD * 2;
    float2* colinfo = (float2*)ws;                       ws += (size_t)BT * NN * 8;
    float* hpart    = (float*)ws;                        ws += (size_t)BT * 8 * DD * 4;
    int* cpart      = (int*)ws;                          ws += (size_t)BT * 8 * 4;
    int* rows       = (int*)ws;

    kpre<<<BT * 8, 256, 0, stream>>>(h, vel, mask, ht, hb16, hpart, cpart, colinfo, rows);
    ktempbeta<<<BB * 64, 256, 0, stream>>>(hb16, mask, hpart, cpart, out);
    kspatial<<<BT * 8, 256, 0, stream>>>(adj, vel, cpart, rows, colinfo, ht, out);
}